// Round 4
// baseline (231.122 us; speedup 1.0000x reference)
//
#include <hip/hip_runtime.h>

// bMomentumLIF forward: x[B,T,F] fp32 -> spikes[B,T,F] fp32
// Recurrence per neuron (b,f) over t:
//   u  = u_last * 0.5 + x[t]            (TAU=2, /2 == *0.5 exactly)
//   s  = (u - th >= 0) ? 1 : 0
//   m  = mt*m + (1-mt)*(u - u_last)
//   u' = (u*lb + m*(1-lb)) * (1-s)
//
// R4: R3 (float4 + nontemporal, -9us) with the pipeline deepened 2 -> 4.
// Rationale: kernel est. ~66us vs ~43us BW floor; 2048 waves = 2/SIMD and
// depth-2 prefetch leaves BW delivery sensitive to conservative vmcnt
// placement (stores share vmcnt). Depth-4 with named rotating registers
// (static indexing -> no scratch) gives 4 KiB in flight per wave
// (32 KB/CU vs 9.2 KB needed for 6.3 TB/s at ~900cy latency).
// #pragma unroll 1 forbids the full-unroll register-hoisting pathology.
// Arithmetic order unchanged, fp contract off -> absmax stays 0.

constexpr int B  = 64;
constexpr int T  = 64;
constexpr int F  = 8192;
constexpr int F4 = F / 4;   // float4 granularity along F (2048)

typedef float fvec4 __attribute__((ext_vector_type(4)));

__device__ __forceinline__ fvec4 lif_step(const fvec4 xi, fvec4& u, fvec4& m,
                                          const float mt, const float omt,
                                          const float lb, const float olb,
                                          const float th)
{
    // Disable FMA contraction: spike threshold is exact-compare against the
    // numpy fp32 reference; contraction changes rounding of the m-update and
    // can flip spikes at the boundary (error 1.0).
#pragma clang fp contract(off)
    fvec4 sv;
    // component 0
    {
        const float uu = u.x * 0.5f + xi.x;
        const float s  = ((uu - th) >= 0.0f) ? 1.0f : 0.0f;
        const float a  = mt * m.x;
        const float bq = omt * (uu - u.x);
        m.x = a + bq;
        u.x = (uu * lb + m.x * olb) * (1.0f - s);
        sv.x = s;
    }
    // component 1
    {
        const float uu = u.y * 0.5f + xi.y;
        const float s  = ((uu - th) >= 0.0f) ? 1.0f : 0.0f;
        const float a  = mt * m.y;
        const float bq = omt * (uu - u.y);
        m.y = a + bq;
        u.y = (uu * lb + m.y * olb) * (1.0f - s);
        sv.y = s;
    }
    // component 2
    {
        const float uu = u.z * 0.5f + xi.z;
        const float s  = ((uu - th) >= 0.0f) ? 1.0f : 0.0f;
        const float a  = mt * m.z;
        const float bq = omt * (uu - u.z);
        m.z = a + bq;
        u.z = (uu * lb + m.z * olb) * (1.0f - s);
        sv.z = s;
    }
    // component 3
    {
        const float uu = u.w * 0.5f + xi.w;
        const float s  = ((uu - th) >= 0.0f) ? 1.0f : 0.0f;
        const float a  = mt * m.w;
        const float bq = omt * (uu - u.w);
        m.w = a + bq;
        u.w = (uu * lb + m.w * olb) * (1.0f - s);
        sv.w = s;
    }
    return sv;
}

__global__ __launch_bounds__(256) void lif_fwd_kernel(
    const fvec4* __restrict__ x,
    const float* __restrict__ momentum,
    const float* __restrict__ lamb,
    const float* __restrict__ thresholds,
    fvec4*       __restrict__ out)
{
    const int tid = blockIdx.x * blockDim.x + threadIdx.x;   // 0 .. B*F4-1
    const int b   = tid >> 11;            // tid / F4   (F4 == 2048)
    const int f4  = tid & (F4 - 1);

    const float mt  = momentum[0];
    const float omt = 1.0f - mt;
    const float lb  = lamb[0];
    const float olb = 1.0f - lb;
    const float th  = thresholds[0];

    int idx = b * (T * F4) + f4;   // float4 index; stride F4 per timestep

    fvec4 u = {0.0f, 0.0f, 0.0f, 0.0f};
    fvec4 m = {0.0f, 0.0f, 0.0f, 0.0f};

    // 4-deep software pipeline, named rotating registers (static indexing).
    fvec4 p0 = __builtin_nontemporal_load(&x[idx]);
    fvec4 p1 = __builtin_nontemporal_load(&x[idx + F4]);
    fvec4 p2 = __builtin_nontemporal_load(&x[idx + 2 * F4]);
    fvec4 p3 = __builtin_nontemporal_load(&x[idx + 3 * F4]);

#pragma unroll 1
    for (int t = 0; t < T; t += 4) {
        // slot 0: element t
        {
            const int poff = (t + 4 < T) ? 4 * F4 : 0;   // clamp on tail
            const fvec4 nx = __builtin_nontemporal_load(&x[idx + poff]);
            const fvec4 sv = lif_step(p0, u, m, mt, omt, lb, olb, th);
            __builtin_nontemporal_store(sv, &out[idx]);
            idx += F4;
            p0 = nx;
        }
        // slot 1: element t+1
        {
            const int poff = (t + 5 < T) ? 4 * F4 : 0;
            const fvec4 nx = __builtin_nontemporal_load(&x[idx + poff]);
            const fvec4 sv = lif_step(p1, u, m, mt, omt, lb, olb, th);
            __builtin_nontemporal_store(sv, &out[idx]);
            idx += F4;
            p1 = nx;
        }
        // slot 2: element t+2
        {
            const int poff = (t + 6 < T) ? 4 * F4 : 0;
            const fvec4 nx = __builtin_nontemporal_load(&x[idx + poff]);
            const fvec4 sv = lif_step(p2, u, m, mt, omt, lb, olb, th);
            __builtin_nontemporal_store(sv, &out[idx]);
            idx += F4;
            p2 = nx;
        }
        // slot 3: element t+3
        {
            const int poff = (t + 7 < T) ? 4 * F4 : 0;
            const fvec4 nx = __builtin_nontemporal_load(&x[idx + poff]);
            const fvec4 sv = lif_step(p3, u, m, mt, omt, lb, olb, th);
            __builtin_nontemporal_store(sv, &out[idx]);
            idx += F4;
            p3 = nx;
        }
    }
}

extern "C" void kernel_launch(void* const* d_in, const int* in_sizes, int n_in,
                              void* d_out, int out_size, void* d_ws, size_t ws_size,
                              hipStream_t stream) {
    const fvec4* x   = (const fvec4*)d_in[0];
    const float* mom = (const float*)d_in[1];
    const float* lmb = (const float*)d_in[2];
    const float* thr = (const float*)d_in[3];
    fvec4* out = (fvec4*)d_out;

    const int n_threads = B * F4;          // 131072
    const int block = 256;
    const int grid = n_threads / block;    // 512
    lif_fwd_kernel<<<grid, block, 0, stream>>>(x, mom, lmb, thr, out);
}

// Round 5
// 228.276 us; speedup vs baseline: 1.0125x; 1.0125x over previous
//
#include <hip/hip_runtime.h>

// bMomentumLIF forward: x[B,T,F] fp32 -> spikes[B,T,F] fp32
// Recurrence per neuron (b,f) over t:
//   u  = u_last * 0.5 + x[t]            (TAU=2, /2 == *0.5 exactly)
//   s  = (u - th >= 0) ? 1 : 0
//   m  = mt*m + (1-mt)*(u - u_last)
//   u' = (u*lb + m*(1-lb)) * (1-s)
//
// R5 = R3 (best, 226.6us) with ONE flip: stores are CACHED again, loads
// stay nontemporal. Ledger: R0 236 (cached both) / R1 238 (float2, 2x
// waves) / R3 226.6 (nt both) / R4 231 (depth-4). Scheduling levers are
// all null; only cache policy moved the number. out (128 MiB) FITS the
// 256 MiB L3 -> cached stores can complete at LLC speed with lazy HBM
// write-back, removing the mixed R/W stream from HBM; nt loads keep the
// zero-reuse x stream from evicting those dirty lines.
// Arithmetic order unchanged, fp contract off -> absmax stays 0.

constexpr int B  = 64;
constexpr int T  = 64;
constexpr int F  = 8192;
constexpr int F4 = F / 4;   // float4 granularity along F (2048)

typedef float fvec4 __attribute__((ext_vector_type(4)));

__global__ __launch_bounds__(256) void lif_fwd_kernel(
    const fvec4* __restrict__ x,
    const float* __restrict__ momentum,
    const float* __restrict__ lamb,
    const float* __restrict__ thresholds,
    fvec4*       __restrict__ out)
{
    // Disable FMA contraction: spike threshold is exact-compare against the
    // numpy fp32 reference; contraction changes rounding of the m-update and
    // can flip spikes at the boundary (error 1.0).
#pragma clang fp contract(off)

    const int tid = blockIdx.x * blockDim.x + threadIdx.x;   // 0 .. B*F4-1
    const int b   = tid >> 11;            // tid / F4   (F4 == 2048)
    const int f4  = tid & (F4 - 1);

    const float mt  = momentum[0];
    const float omt = 1.0f - mt;
    const float lb  = lamb[0];
    const float olb = 1.0f - lb;
    const float th  = thresholds[0];

    int idx = b * (T * F4) + f4;   // float4 index; stride F4 per timestep

    float u0 = 0.0f, u1 = 0.0f, u2 = 0.0f, u3 = 0.0f;
    float m0 = 0.0f, m1 = 0.0f, m2 = 0.0f, m3 = 0.0f;

    // 2-deep software pipeline; loads nontemporal (zero-reuse stream).
    fvec4 x0 = __builtin_nontemporal_load(&x[idx]);          // t = 0
    fvec4 x1 = __builtin_nontemporal_load(&x[idx + F4]);     // t = 1

#pragma unroll 2
    for (int t = 0; t < T; ++t) {
        // Prefetch t+2 (clamped on the tail; value discarded there).
        const int poff = (t + 2 < T) ? 2 * F4 : 0;
        const fvec4 xn = __builtin_nontemporal_load(&x[idx + poff]);

        fvec4 sv;

        // component 0
        {
            const float u  = u0 * 0.5f + x0.x;
            const float s  = ((u - th) >= 0.0f) ? 1.0f : 0.0f;
            const float a  = mt * m0;
            const float bq = omt * (u - u0);
            m0 = a + bq;
            u0 = (u * lb + m0 * olb) * (1.0f - s);
            sv.x = s;
        }
        // component 1
        {
            const float u  = u1 * 0.5f + x0.y;
            const float s  = ((u - th) >= 0.0f) ? 1.0f : 0.0f;
            const float a  = mt * m1;
            const float bq = omt * (u - u1);
            m1 = a + bq;
            u1 = (u * lb + m1 * olb) * (1.0f - s);
            sv.y = s;
        }
        // component 2
        {
            const float u  = u2 * 0.5f + x0.z;
            const float s  = ((u - th) >= 0.0f) ? 1.0f : 0.0f;
            const float a  = mt * m2;
            const float bq = omt * (u - u2);
            m2 = a + bq;
            u2 = (u * lb + m2 * olb) * (1.0f - s);
            sv.z = s;
        }
        // component 3
        {
            const float u  = u3 * 0.5f + x0.w;
            const float s  = ((u - th) >= 0.0f) ? 1.0f : 0.0f;
            const float a  = mt * m3;
            const float bq = omt * (u - u3);
            m3 = a + bq;
            u3 = (u * lb + m3 * olb) * (1.0f - s);
            sv.w = s;
        }

        out[idx] = sv;   // cached store: out fits L3, let LLC absorb it
        idx += F4;
        x0 = x1;
        x1 = xn;
    }
}

extern "C" void kernel_launch(void* const* d_in, const int* in_sizes, int n_in,
                              void* d_out, int out_size, void* d_ws, size_t ws_size,
                              hipStream_t stream) {
    const fvec4* x   = (const fvec4*)d_in[0];
    const float* mom = (const float*)d_in[1];
    const float* lmb = (const float*)d_in[2];
    const float* thr = (const float*)d_in[3];
    fvec4* out = (fvec4*)d_out;

    const int n_threads = B * F4;          // 131072
    const int block = 256;
    const int grid = n_threads / block;    // 512
    lif_fwd_kernel<<<grid, block, 0, stream>>>(x, mom, lmb, thr, out);
}

// Round 6
// 224.228 us; speedup vs baseline: 1.0307x; 1.0181x over previous
//
#include <hip/hip_runtime.h>

// bMomentumLIF forward: x[B,T,F] fp32 -> spikes[B,T,F] fp32
// Recurrence per neuron (b,f) over t:
//   u  = u_last * 0.5 + x[t]            (TAU=2, /2 == *0.5 exactly)
//   s  = (u - th >= 0) ? 1 : 0
//   m  = mt*m + (1-mt)*(u - u_last)
//   u' = (u*lb + m*(1-lb)) * (1-s)
//
// R6 = byte-for-byte revert to R3, the best-measured variant (226.6us).
// Ledger: R0 236 (cached) / R1 238 (float2 2x-waves) / R3 226.6 (nt both)
// / R4 231 (depth-4) / R5 228 (nt-load+cached-store). All scheduling,
// occupancy, and store-policy levers are null; nt loads are the only real
// win (-9us). Kernel dispatch est. ~66us (dur_us minus two ~80us harness
// poison fills); remaining gap to the ~45-49us mixed-stream floor is the
// achievable bandwidth of this forced access pattern (serial-over-T
// recurrence, 64 read + 64 write concurrent streams).
// fp contract off; exact op order preserved -> absmax 0.

constexpr int B  = 64;
constexpr int T  = 64;
constexpr int F  = 8192;
constexpr int F4 = F / 4;   // float4 granularity along F (2048)

typedef float fvec4 __attribute__((ext_vector_type(4)));

__global__ __launch_bounds__(256) void lif_fwd_kernel(
    const fvec4* __restrict__ x,
    const float* __restrict__ momentum,
    const float* __restrict__ lamb,
    const float* __restrict__ thresholds,
    fvec4*       __restrict__ out)
{
    // Disable FMA contraction: spike threshold is exact-compare against the
    // numpy fp32 reference; contraction changes rounding of the m-update and
    // can flip spikes at the boundary (error 1.0).
#pragma clang fp contract(off)

    const int tid = blockIdx.x * blockDim.x + threadIdx.x;   // 0 .. B*F4-1
    const int b   = tid >> 11;            // tid / F4   (F4 == 2048)
    const int f4  = tid & (F4 - 1);

    const float mt  = momentum[0];
    const float omt = 1.0f - mt;
    const float lb  = lamb[0];
    const float olb = 1.0f - lb;
    const float th  = thresholds[0];

    int idx = b * (T * F4) + f4;   // float4 index; stride F4 per timestep

    float u0 = 0.0f, u1 = 0.0f, u2 = 0.0f, u3 = 0.0f;
    float m0 = 0.0f, m1 = 0.0f, m2 = 0.0f, m3 = 0.0f;

    // 2-deep software pipeline with nontemporal (cache-bypassing) loads.
    fvec4 x0 = __builtin_nontemporal_load(&x[idx]);          // t = 0
    fvec4 x1 = __builtin_nontemporal_load(&x[idx + F4]);     // t = 1

#pragma unroll 2
    for (int t = 0; t < T; ++t) {
        // Prefetch t+2 (clamped on the tail; value discarded there).
        const int poff = (t + 2 < T) ? 2 * F4 : 0;
        const fvec4 xn = __builtin_nontemporal_load(&x[idx + poff]);

        fvec4 sv;

        // component 0
        {
            const float u  = u0 * 0.5f + x0.x;
            const float s  = ((u - th) >= 0.0f) ? 1.0f : 0.0f;
            const float a  = mt * m0;
            const float bq = omt * (u - u0);
            m0 = a + bq;
            u0 = (u * lb + m0 * olb) * (1.0f - s);
            sv.x = s;
        }
        // component 1
        {
            const float u  = u1 * 0.5f + x0.y;
            const float s  = ((u - th) >= 0.0f) ? 1.0f : 0.0f;
            const float a  = mt * m1;
            const float bq = omt * (u - u1);
            m1 = a + bq;
            u1 = (u * lb + m1 * olb) * (1.0f - s);
            sv.y = s;
        }
        // component 2
        {
            const float u  = u2 * 0.5f + x0.z;
            const float s  = ((u - th) >= 0.0f) ? 1.0f : 0.0f;
            const float a  = mt * m2;
            const float bq = omt * (u - u2);
            m2 = a + bq;
            u2 = (u * lb + m2 * olb) * (1.0f - s);
            sv.z = s;
        }
        // component 3
        {
            const float u  = u3 * 0.5f + x0.w;
            const float s  = ((u - th) >= 0.0f) ? 1.0f : 0.0f;
            const float a  = mt * m3;
            const float bq = omt * (u - u3);
            m3 = a + bq;
            u3 = (u * lb + m3 * olb) * (1.0f - s);
            sv.w = s;
        }

        __builtin_nontemporal_store(sv, &out[idx]);
        idx += F4;
        x0 = x1;
        x1 = xn;
    }
}

extern "C" void kernel_launch(void* const* d_in, const int* in_sizes, int n_in,
                              void* d_out, int out_size, void* d_ws, size_t ws_size,
                              hipStream_t stream) {
    const fvec4* x   = (const fvec4*)d_in[0];
    const float* mom = (const float*)d_in[1];
    const float* lmb = (const float*)d_in[2];
    const float* thr = (const float*)d_in[3];
    fvec4* out = (fvec4*)d_out;

    const int n_threads = B * F4;          // 131072
    const int block = 256;
    const int grid = n_threads / block;    // 512
    lif_fwd_kernel<<<grid, block, 0, stream>>>(x, mom, lmb, thr, out);
}